// Round 6
// baseline (205.588 us; speedup 1.0000x reference)
//
#include <hip/hip_runtime.h>
#include <hip/hip_bf16.h>

using bf16 = __hip_bfloat16;
typedef __attribute__((ext_vector_type(8))) short short8;   // 8 bf16 = 4 VGPRs (MFMA A/B frag)
typedef __attribute__((ext_vector_type(4))) float floatx4;  // MFMA C/D frag

#define B_  2
#define T_  2048
#define C_  1024
#define H_  16
#define HD_ 64
#define BT_ (B_*T_)
#define NX_ ((size_t)BT_*C_)   /* 4M elems */
#define NW_ ((size_t)C_*C_)    /* 1M elems */
#define PSTR 136               /* Ps row stride in elems: 272B, 16B-aligned */
#define KSCQ 0.1803368801f     /* (1/sqrt(64)) * log2(e), folded into Q at qkv epilogue */

// async global->LDS, 16B per lane. LDS dest is wave-uniform base; lane i lands at base + i*16B.
__device__ __forceinline__ void gl2lds16(const bf16* g, bf16* l) {
    __builtin_amdgcn_global_load_lds((const __attribute__((address_space(1))) unsigned int*)g,
                                     (__attribute__((address_space(3))) unsigned int*)l,
                                     16, 0, 0);
}

// ---------------------------------------------------------------------------
// Kernel 0: f32 -> bf16 conversion for x and the 4 weight matrices.
// ---------------------------------------------------------------------------
__global__ __launch_bounds__(256) void cvt_f32_bf16(
    const float* __restrict__ x,
    const float* __restrict__ Wq, const float* __restrict__ Wk,
    const float* __restrict__ Wv, const float* __restrict__ Wp,
    bf16* __restrict__ xb, bf16* __restrict__ wqb, bf16* __restrict__ wkb,
    bf16* __restrict__ wvb, bf16* __restrict__ wpb)
{
    size_t i4 = ((size_t)blockIdx.x * 256 + threadIdx.x) * 4;
    const float* src; bf16* dst; size_t off;
    if (i4 < NX_) { src = x; dst = xb; off = i4; }
    else {
        size_t j = i4 - NX_;
        int r = (int)(j >> 20);
        off = j & (NW_ - 1);
        src = (r==0) ? Wq : (r==1) ? Wk : (r==2) ? Wv : Wp;
        dst = (r==0) ? wqb : (r==1) ? wkb : (r==2) ? wvb : wpb;
    }
    float4 v = *(const float4*)(src + off);
    union { bf16 h[4]; uint2 u; } o;
    o.h[0] = __float2bfloat16(v.x); o.h[1] = __float2bfloat16(v.y);
    o.h[2] = __float2bfloat16(v.z); o.h[3] = __float2bfloat16(v.w);
    *(uint2*)(dst + off) = o.u;
}

// ---------------------------------------------------------------------------
// Kernel A: fused QKV projection.  y = x @ W^T + b for W in {Wq,Wk,Wv}.
// Grid (32 mtiles, 24 ntiles). ntile/8 selects the weight. 128x128 tile, BK=32.
// Q stored PRE-SCALED by KSCQ; Q,K stored [B,T,C]; V stored [B,H,HD,T].
// ---------------------------------------------------------------------------
__global__ __launch_bounds__(256) void qkv_gemm(
    const bf16* __restrict__ x,
    const bf16* __restrict__ Wq, const float* __restrict__ bq,
    const bf16* __restrict__ Wk, const float* __restrict__ bk,
    const bf16* __restrict__ Wv, const float* __restrict__ bv,
    bf16* __restrict__ qo, bf16* __restrict__ ko, bf16* __restrict__ vt)
{
    __shared__ __align__(16) bf16 As[128*32];
    __shared__ __align__(16) bf16 Bs[128*32];

    const int tid  = threadIdx.x;
    const int w    = tid >> 6, lane = tid & 63;
    const int g    = lane >> 4, c16 = lane & 15;
    const int wr   = w >> 1,    wc  = w & 1;
    const int mtile = blockIdx.x, ntile = blockIdx.y;
    const int wsel  = ntile >> 3;                 // 0=Q 1=K 2=V (uniform per block)
    const bf16*  W    = (wsel==0) ? Wq : (wsel==1 ? Wk : Wv);
    const float* bias = (wsel==0) ? bq : (wsel==1 ? bk : bv);
    const float oscale = (wsel==0) ? KSCQ : 1.0f;
    const int nbase  = (ntile & 7) * 128;

    const bf16* ag = x + (size_t)(mtile*128)*C_;
    const bf16* bg = W + (size_t)nbase*C_;

    floatx4 acc[4][4] = {};

    for (int k0 = 0; k0 < C_; k0 += 32) {
        #pragma unroll
        for (int p = 0; p < 2; ++p) {
            int cb = p*256 + w*64;        // wave-uniform chunk base
            int c  = cb + lane;           // this lane's chunk: row=c>>2, colgrp=c&3
            gl2lds16(ag + (size_t)(c>>2)*C_ + k0 + (c&3)*8, As + cb*8);
            gl2lds16(bg + (size_t)(c>>2)*C_ + k0 + (c&3)*8, Bs + cb*8);
        }
        __syncthreads();

        short8 af[4], bfr[4];
        #pragma unroll
        for (int i = 0; i < 4; ++i)
            af[i] = *(const short8*)(As + (wr*64 + i*16 + c16)*32 + g*8);
        #pragma unroll
        for (int j = 0; j < 4; ++j)
            bfr[j] = *(const short8*)(Bs + (wc*64 + j*16 + c16)*32 + g*8);
        #pragma unroll
        for (int i = 0; i < 4; ++i)
            #pragma unroll
            for (int j = 0; j < 4; ++j)
                acc[i][j] = __builtin_amdgcn_mfma_f32_16x16x32_bf16(af[i], bfr[j], acc[i][j], 0, 0, 0);
        __syncthreads();
    }

    // Epilogue. C/D layout: row=(lane>>4)*4+reg, col=lane&15.
    #pragma unroll
    for (int i = 0; i < 4; ++i) {
        int m0 = mtile*128 + wr*64 + i*16 + g*4;     // 4 consecutive rows m0..m0+3
        #pragma unroll
        for (int j = 0; j < 4; ++j) {
            int n = nbase + wc*64 + j*16 + c16;      // output channel 0..1023
            float bvf = bias[n];
            if (wsel == 2) {
                // V transposed: vt[b][h][hd][t]; 4 regs = 4 consecutive t -> one 8B store
                int bb = m0 >> 11, t0 = m0 & (T_-1);
                int hh = n >> 6,  hd = n & 63;
                union { bf16 hv[4]; uint2 u; } tmp;
                #pragma unroll
                for (int r = 0; r < 4; ++r) tmp.hv[r] = __float2bfloat16(acc[i][j][r] + bvf);
                *(uint2*)(vt + ((size_t)((bb*H_ + hh)*64 + hd))*T_ + t0) = tmp.u;
            } else {
                bf16* dst = (wsel==0) ? qo : ko;
                #pragma unroll
                for (int r = 0; r < 4; ++r)
                    dst[(size_t)(m0+r)*C_ + n] = __float2bfloat16((acc[i][j][r] + bvf) * oscale);
            }
        }
    }
}

// ---------------------------------------------------------------------------
// Kernel B v5: causal flash attention, transposed-S softmax + balanced pairs.
// Q comes in pre-scaled by KSCQ so S is already in log2 units: exp = exp2(s-mn).
// Softmax uses tree max, 4-way partial sums, packed bf16 cvt -> shorter VALU
// chains (the r5 bottleneck: VALUBusy 45%, serial fmax/add chains).
// ---------------------------------------------------------------------------
__global__ __launch_bounds__(256) void attn(
    const bf16* __restrict__ q, const bf16* __restrict__ k,
    const bf16* __restrict__ vt, bf16* __restrict__ y)
{
    __shared__ __align__(16) bf16 Ks[16*512];      // frag f=(ct*2+kg): K[ct*16+c16][kg*32+g*8..+8]
    __shared__ __align__(16) bf16 Vs[16*512];      // frag f=(ks*4+nt): Vt[nt*16+c16][ks*32+g*8..+8]
    __shared__ __align__(16) bf16 Ps[4][16*PSTR];  // per-wave P [q][key], padded

    const int tid = threadIdx.x, w = tid >> 6, lane = tid & 63;
    const int g = lane >> 4, c16 = lane & 15;
    const int jj = blockIdx.x, h = blockIdx.y, b = blockIdx.z;

    const bf16* kbase = k  + ((size_t)(b*T_))*C_ + h*64;
    const bf16* vbase = vt + ((size_t)(b*H_ + h))*64*T_;

    #pragma unroll 1
    for (int seg = 0; seg < 2; ++seg) {
        const int qt = seg ? jj : 31 - jj;        // long segment first
        const int qbase = qt*64 + w*16;           // global q-row base for this wave
        const int nit = (qt + 2) >> 1;            // # 128-key tiles (causal)
        const int qglob = qbase + c16;            // this lane's q row (S^T col)

        // Q frag (B-operand): [q=c16][d=g*8+j], pre-scaled by KSCQ
        short8 aq[2];
        #pragma unroll
        for (int kg = 0; kg < 2; ++kg)
            aq[kg] = *(const short8*)(q + ((size_t)(b*T_ + qglob))*C_ + h*64 + kg*32 + g*8);

        floatx4 accO[4] = {};
        float m_l = -1e30f, l_l = 0.f;            // per-lane (per-q) softmax state

        for (int kt = 0; kt < nit; ++kt) {
            // stage 16+16 fragments; wave w stages frags f = w*4+p (wave-uniform)
            #pragma unroll
            for (int p = 0; p < 4; ++p) {
                int f = w*4 + p;
                int ctk = f >> 1, kg = f & 1;
                gl2lds16(kbase + (size_t)(kt*128 + ctk*16 + c16)*C_ + kg*32 + g*8, Ks + f*512);
                gl2lds16(vbase + (size_t)(p*16 + c16)*T_ + kt*128 + w*32 + g*8,    Vs + f*512);
            }
            __syncthreads();

            // S^T = K Q^T : D[key=g*4+r (per ct)][q=c16]  (log2-scaled)
            floatx4 s[8];
            #pragma unroll
            for (int ct = 0; ct < 8; ++ct) {
                floatx4 a = {0.f, 0.f, 0.f, 0.f};
                #pragma unroll
                for (int kg = 0; kg < 2; ++kg) {
                    short8 kb = *(const short8*)(Ks + (ct*2 + kg)*512 + lane*8);
                    a = __builtin_amdgcn_mfma_f32_16x16x32_bf16(kb, aq[kg], a, 0, 0, 0);
                }
                s[ct] = a;
            }

            if (kt == nit-1) {   // causal mask: key > q  (all operands lane-local)
                #pragma unroll
                for (int ct = 0; ct < 8; ++ct)
                    #pragma unroll
                    for (int r = 0; r < 4; ++r) {
                        int key = kt*128 + ct*16 + g*4 + r;
                        if (key > qglob) s[ct][r] = -1e30f;
                    }
            }

            // tree max over 32 in-lane values + 2 shfls across the 4 g-lanes
            float cm[8];
            #pragma unroll
            for (int ct = 0; ct < 8; ++ct)
                cm[ct] = fmaxf(fmaxf(s[ct][0], s[ct][1]), fmaxf(s[ct][2], s[ct][3]));
            float tmax = fmaxf(fmaxf(fmaxf(cm[0], cm[1]), fmaxf(cm[2], cm[3])),
                               fmaxf(fmaxf(cm[4], cm[5]), fmaxf(cm[6], cm[7])));
            tmax = fmaxf(tmax, __shfl_xor(tmax, 16));
            tmax = fmaxf(tmax, __shfl_xor(tmax, 32));
            float mn = fmaxf(m_l, tmax);
            float alpha = exp2f(m_l - mn);
            m_l = mn;

            // exp pass: 4 independent partial-sum chains, packed bf16 stores
            float s0 = 0.f, s1 = 0.f, s2 = 0.f, s3 = 0.f;
            #pragma unroll
            for (int ct = 0; ct < 8; ++ct) {
                float p0 = exp2f(s[ct][0] - mn);
                float p1 = exp2f(s[ct][1] - mn);
                float p2 = exp2f(s[ct][2] - mn);
                float p3 = exp2f(s[ct][3] - mn);
                s0 += p0; s1 += p1; s2 += p2; s3 += p3;
                union { __hip_bfloat162 h2[2]; uint2 u; } pk;
                pk.h2[0] = __float22bfloat162_rn(float2{p0, p1});
                pk.h2[1] = __float22bfloat162_rn(float2{p2, p3});
                *(uint2*)(Ps[w] + c16*PSTR + ct*16 + g*4) = pk.u;   // keys g*4..+3
            }
            float tsum = (s0 + s1) + (s2 + s3);
            tsum += __shfl_xor(tsum, 16);
            tsum += __shfl_xor(tsum, 32);
            l_l = l_l*alpha + tsum;

            // broadcast alpha from q-lanes to C-layout rows (q = g*4+r)
            float ar[4];
            #pragma unroll
            for (int r = 0; r < 4; ++r) ar[r] = __shfl(alpha, g*4 + r);
            #pragma unroll
            for (int nt = 0; nt < 4; ++nt)
                #pragma unroll
                for (int r = 0; r < 4; ++r) accO[nt][r] *= ar[r];

            // O += P V : A=P[q][key], B=V^T frags (sequential reads)
            #pragma unroll
            for (int ks = 0; ks < 4; ++ks) {
                short8 pa = *(const short8*)(Ps[w] + c16*PSTR + ks*32 + g*8);
                #pragma unroll
                for (int nt = 0; nt < 4; ++nt) {
                    short8 vb = *(const short8*)(Vs + (ks*4 + nt)*512 + lane*8);
                    accO[nt] = __builtin_amdgcn_mfma_f32_16x16x32_bf16(pa, vb, accO[nt], 0, 0, 0);
                }
            }
            __syncthreads();
        }

        // epilogue: y[b,t,h*64+d] = O * (1/l) ; l broadcast like alpha, v_rcp
        float ir[4];
        #pragma unroll
        for (int r = 0; r < 4; ++r) ir[r] = __builtin_amdgcn_rcpf(__shfl(l_l, g*4 + r));
        #pragma unroll
        for (int nt = 0; nt < 4; ++nt)
            #pragma unroll
            for (int r = 0; r < 4; ++r) {
                int row = qbase + g*4 + r;
                float o = accO[nt][r] * ir[r];
                y[((size_t)(b*T_ + row))*C_ + h*64 + nt*16 + c16] = __float2bfloat16(o);
            }
    }
}

// ---------------------------------------------------------------------------
// Kernel C: output projection. out = y_att @ Wp^T + bp (f32 output). Grid (32, 8).
// ---------------------------------------------------------------------------
__global__ __launch_bounds__(256) void proj_gemm(
    const bf16* __restrict__ yin, const bf16* __restrict__ Wp, const float* __restrict__ bp,
    float* __restrict__ out)
{
    __shared__ __align__(16) bf16 As[128*32];
    __shared__ __align__(16) bf16 Bs[128*32];

    const int tid = threadIdx.x;
    const int w = tid >> 6, lane = tid & 63;
    const int g = lane >> 4, c16 = lane & 15;
    const int wr = w >> 1, wc = w & 1;
    const int mtile = blockIdx.x, ntile = blockIdx.y;
    const int nbase = ntile * 128;

    const bf16* ag = yin + (size_t)(mtile*128)*C_;
    const bf16* bg = Wp  + (size_t)nbase*C_;

    floatx4 acc[4][4] = {};

    for (int k0 = 0; k0 < C_; k0 += 32) {
        #pragma unroll
        for (int p = 0; p < 2; ++p) {
            int cb = p*256 + w*64;
            int c  = cb + lane;
            gl2lds16(ag + (size_t)(c>>2)*C_ + k0 + (c&3)*8, As + cb*8);
            gl2lds16(bg + (size_t)(c>>2)*C_ + k0 + (c&3)*8, Bs + cb*8);
        }
        __syncthreads();

        short8 af[4], bfr[4];
        #pragma unroll
        for (int i = 0; i < 4; ++i)
            af[i] = *(const short8*)(As + (wr*64 + i*16 + c16)*32 + g*8);
        #pragma unroll
        for (int j = 0; j < 4; ++j)
            bfr[j] = *(const short8*)(Bs + (wc*64 + j*16 + c16)*32 + g*8);
        #pragma unroll
        for (int i = 0; i < 4; ++i)
            #pragma unroll
            for (int j = 0; j < 4; ++j)
                acc[i][j] = __builtin_amdgcn_mfma_f32_16x16x32_bf16(af[i], bfr[j], acc[i][j], 0, 0, 0);
        __syncthreads();
    }

    #pragma unroll
    for (int i = 0; i < 4; ++i) {
        int m0 = mtile*128 + wr*64 + i*16 + g*4;
        #pragma unroll
        for (int j = 0; j < 4; ++j) {
            int n = nbase + wc*64 + j*16 + c16;
            float bvf = bp[n];
            #pragma unroll
            for (int r = 0; r < 4; ++r)
                out[(size_t)(m0+r)*C_ + n] = acc[i][j][r] + bvf;
        }
    }
}

extern "C" void kernel_launch(void* const* d_in, const int* in_sizes, int n_in,
                              void* d_out, int out_size, void* d_ws, size_t ws_size,
                              hipStream_t stream) {
    const float* x  = (const float*)d_in[0];
    const float* Wq = (const float*)d_in[1];
    const float* bq = (const float*)d_in[2];
    const float* Wk = (const float*)d_in[3];
    const float* bk = (const float*)d_in[4];
    const float* Wv = (const float*)d_in[5];
    const float* bv = (const float*)d_in[6];
    const float* Wp = (const float*)d_in[7];
    const float* bp = (const float*)d_in[8];

    // workspace layout (bf16 elements)
    bf16* xb  = (bf16*)d_ws;          // 4M
    bf16* wqb = xb  + NX_;            // 1M
    bf16* wkb = wqb + NW_;            // 1M
    bf16* wvb = wkb + NW_;            // 1M
    bf16* wpb = wvb + NW_;            // 1M
    bf16* qw  = wpb + NW_;            // 4M
    bf16* kw  = qw  + NX_;            // 4M
    bf16* vt  = kw  + NX_;            // 4M
    bf16* yw  = vt  + NX_;            // 4M  -> total 24M bf16 = 48 MB

    const int cvt_blocks = (int)((NX_ + 4*NW_) / (4*256));   // 8192
    cvt_f32_bf16<<<cvt_blocks, 256, 0, stream>>>(x, Wq, Wk, Wv, Wp, xb, wqb, wkb, wvb, wpb);
    qkv_gemm<<<dim3(32, 24), 256, 0, stream>>>(xb, wqb, bq, wkb, bk, wvb, bv, qw, kw, vt);
    attn    <<<dim3(16, H_, B_), 256, 0, stream>>>(qw, kw, vt, yw);
    proj_gemm<<<dim3(32, 8), 256, 0, stream>>>(yw, wpb, bp, (float*)d_out);
}

// Round 7
// 204.060 us; speedup vs baseline: 1.0075x; 1.0075x over previous
//
#include <hip/hip_runtime.h>
#include <hip/hip_bf16.h>

using bf16 = __hip_bfloat16;
typedef __attribute__((ext_vector_type(8))) short short8;   // 8 bf16 = 4 VGPRs (MFMA A/B frag)
typedef __attribute__((ext_vector_type(4))) float floatx4;  // MFMA C/D frag

#define B_  2
#define T_  2048
#define C_  1024
#define H_  16
#define HD_ 64
#define BT_ (B_*T_)
#define NX_ ((size_t)BT_*C_)   /* 4M elems */
#define NW_ ((size_t)C_*C_)    /* 1M elems */
#define PSTR2 40               /* Ps chunk row stride (elems): 80B, 16B-aligned, ~2-way banks */
#define KSCQ 0.1803368801f     /* (1/sqrt(64)) * log2(e), folded into Q at qkv epilogue */

// async global->LDS, 16B per lane. LDS dest is wave-uniform base; lane i lands at base + i*16B.
__device__ __forceinline__ void gl2lds16(const bf16* g, bf16* l) {
    __builtin_amdgcn_global_load_lds((const __attribute__((address_space(1))) unsigned int*)g,
                                     (__attribute__((address_space(3))) unsigned int*)l,
                                     16, 0, 0);
}

// ---------------------------------------------------------------------------
// Kernel 0: f32 -> bf16 conversion for x and the 4 weight matrices.
// ---------------------------------------------------------------------------
__global__ __launch_bounds__(256) void cvt_f32_bf16(
    const float* __restrict__ x,
    const float* __restrict__ Wq, const float* __restrict__ Wk,
    const float* __restrict__ Wv, const float* __restrict__ Wp,
    bf16* __restrict__ xb, bf16* __restrict__ wqb, bf16* __restrict__ wkb,
    bf16* __restrict__ wvb, bf16* __restrict__ wpb)
{
    size_t i4 = ((size_t)blockIdx.x * 256 + threadIdx.x) * 4;
    const float* src; bf16* dst; size_t off;
    if (i4 < NX_) { src = x; dst = xb; off = i4; }
    else {
        size_t j = i4 - NX_;
        int r = (int)(j >> 20);
        off = j & (NW_ - 1);
        src = (r==0) ? Wq : (r==1) ? Wk : (r==2) ? Wv : Wp;
        dst = (r==0) ? wqb : (r==1) ? wkb : (r==2) ? wvb : wpb;
    }
    float4 v = *(const float4*)(src + off);
    union { bf16 h[4]; uint2 u; } o;
    o.h[0] = __float2bfloat16(v.x); o.h[1] = __float2bfloat16(v.y);
    o.h[2] = __float2bfloat16(v.z); o.h[3] = __float2bfloat16(v.w);
    *(uint2*)(dst + off) = o.u;
}

// ---------------------------------------------------------------------------
// Kernel A: fused QKV projection.  y = x @ W^T + b for W in {Wq,Wk,Wv}.
// Grid (32 mtiles, 24 ntiles). ntile/8 selects the weight. 128x128 tile, BK=32.
// Q stored PRE-SCALED by KSCQ; Q,K stored [B,T,C]; V stored [B,H,HD,T].
// ---------------------------------------------------------------------------
__global__ __launch_bounds__(256) void qkv_gemm(
    const bf16* __restrict__ x,
    const bf16* __restrict__ Wq, const float* __restrict__ bq,
    const bf16* __restrict__ Wk, const float* __restrict__ bk,
    const bf16* __restrict__ Wv, const float* __restrict__ bv,
    bf16* __restrict__ qo, bf16* __restrict__ ko, bf16* __restrict__ vt)
{
    __shared__ __align__(16) bf16 As[128*32];
    __shared__ __align__(16) bf16 Bs[128*32];

    const int tid  = threadIdx.x;
    const int w    = tid >> 6, lane = tid & 63;
    const int g    = lane >> 4, c16 = lane & 15;
    const int wr   = w >> 1,    wc  = w & 1;
    const int mtile = blockIdx.x, ntile = blockIdx.y;
    const int wsel  = ntile >> 3;                 // 0=Q 1=K 2=V (uniform per block)
    const bf16*  W    = (wsel==0) ? Wq : (wsel==1 ? Wk : Wv);
    const float* bias = (wsel==0) ? bq : (wsel==1 ? bk : bv);
    const float oscale = (wsel==0) ? KSCQ : 1.0f;
    const int nbase  = (ntile & 7) * 128;

    const bf16* ag = x + (size_t)(mtile*128)*C_;
    const bf16* bg = W + (size_t)nbase*C_;

    floatx4 acc[4][4] = {};

    for (int k0 = 0; k0 < C_; k0 += 32) {
        #pragma unroll
        for (int p = 0; p < 2; ++p) {
            int cb = p*256 + w*64;        // wave-uniform chunk base
            int c  = cb + lane;           // this lane's chunk: row=c>>2, colgrp=c&3
            gl2lds16(ag + (size_t)(c>>2)*C_ + k0 + (c&3)*8, As + cb*8);
            gl2lds16(bg + (size_t)(c>>2)*C_ + k0 + (c&3)*8, Bs + cb*8);
        }
        __syncthreads();

        short8 af[4], bfr[4];
        #pragma unroll
        for (int i = 0; i < 4; ++i)
            af[i] = *(const short8*)(As + (wr*64 + i*16 + c16)*32 + g*8);
        #pragma unroll
        for (int j = 0; j < 4; ++j)
            bfr[j] = *(const short8*)(Bs + (wc*64 + j*16 + c16)*32 + g*8);
        #pragma unroll
        for (int i = 0; i < 4; ++i)
            #pragma unroll
            for (int j = 0; j < 4; ++j)
                acc[i][j] = __builtin_amdgcn_mfma_f32_16x16x32_bf16(af[i], bfr[j], acc[i][j], 0, 0, 0);
        __syncthreads();
    }

    // Epilogue. C/D layout: row=(lane>>4)*4+reg, col=lane&15.
    #pragma unroll
    for (int i = 0; i < 4; ++i) {
        int m0 = mtile*128 + wr*64 + i*16 + g*4;     // 4 consecutive rows m0..m0+3
        #pragma unroll
        for (int j = 0; j < 4; ++j) {
            int n = nbase + wc*64 + j*16 + c16;      // output channel 0..1023
            float bvf = bias[n];
            if (wsel == 2) {
                // V transposed: vt[b][h][hd][t]; 4 regs = 4 consecutive t -> one 8B store
                int bb = m0 >> 11, t0 = m0 & (T_-1);
                int hh = n >> 6,  hd = n & 63;
                union { bf16 hv[4]; uint2 u; } tmp;
                #pragma unroll
                for (int r = 0; r < 4; ++r) tmp.hv[r] = __float2bfloat16(acc[i][j][r] + bvf);
                *(uint2*)(vt + ((size_t)((bb*H_ + hh)*64 + hd))*T_ + t0) = tmp.u;
            } else {
                bf16* dst = (wsel==0) ? qo : ko;
                #pragma unroll
                for (int r = 0; r < 4; ++r)
                    dst[(size_t)(m0+r)*C_ + n] = __float2bfloat16((acc[i][j][r] + bvf) * oscale);
            }
        }
    }
}

// ---------------------------------------------------------------------------
// Kernel B v6: causal flash attention — occupancy package.
// Grid 1024 blocks (1 q-tile of 64 rows each). Balance under round-robin
// block->CU: qt = (h&8) ? 31-qraw : qraw, so CU c's 4 resident blocks carry
// {qt, 31-qt} x2 = 34 iters uniformly. LDS 37.9KB -> 4 blocks/CU.
// Ps is a per-wave 32-key chunk reused over 4 ks-phases; l accumulated via
// ones-MFMA (lands in accO row layout: epilogue needs no shuffles).
// ---------------------------------------------------------------------------
__global__ __launch_bounds__(256, 4) void attn(
    const bf16* __restrict__ q, const bf16* __restrict__ k,
    const bf16* __restrict__ vt, bf16* __restrict__ y)
{
    __shared__ __align__(16) bf16 Ks[16*512];       // 16KB: frag f=(ct*2+kg)
    __shared__ __align__(16) bf16 Vs[16*512];       // 16KB: frag f=(ks*4+nt)
    __shared__ __align__(16) bf16 Ps[4][16*PSTR2];  // 5KB: per-wave 32-key chunk

    const int tid = threadIdx.x, w = tid >> 6, lane = tid & 63;
    const int g = lane >> 4, c16 = lane & 15;
    const int beta = blockIdx.x;
    const int qraw = beta & 31, rhi = beta >> 5;
    const int h = rhi & 15, b = rhi >> 4;
    const int qt = (h & 8) ? 31 - qraw : qraw;    // per-CU balance
    const int qbase = qt*64 + w*16;               // global q-row base for this wave
    const int nit = (qt + 2) >> 1;                // # 128-key tiles (causal)
    const int qglob = qbase + c16;                // this lane's q row (S^T col)

    const bf16* kbase = k  + ((size_t)(b*T_))*C_ + h*64;
    const bf16* vbase = vt + ((size_t)(b*H_ + h))*64*T_;

    // Q frag (B-operand): [q=c16][d=g*8+j], pre-scaled by KSCQ
    short8 aq[2];
    #pragma unroll
    for (int kg = 0; kg < 2; ++kg)
        aq[kg] = *(const short8*)(q + ((size_t)(b*T_ + qglob))*C_ + h*64 + kg*32 + g*8);

    const short ONEB = 0x3F80;                    // bf16 1.0
    const short8 ones = {ONEB,ONEB,ONEB,ONEB,ONEB,ONEB,ONEB,ONEB};

    floatx4 accO[4] = {};
    floatx4 lacc = {};                            // l in accO row layout (all cols equal)
    float m_l = -1e30f;                           // per-lane (per-q) running max

    for (int kt = 0; kt < nit; ++kt) {
        // stage 16+16 fragments; wave w stages frags f = w*4+p (wave-uniform)
        #pragma unroll
        for (int p = 0; p < 4; ++p) {
            int f = w*4 + p;
            int ctk = f >> 1, kg = f & 1;
            gl2lds16(kbase + (size_t)(kt*128 + ctk*16 + c16)*C_ + kg*32 + g*8, Ks + f*512);
            gl2lds16(vbase + (size_t)(p*16 + c16)*T_ + kt*128 + w*32 + g*8,    Vs + f*512);
        }
        __syncthreads();

        // S^T = K Q^T : D[key=g*4+r (per ct)][q=c16]  (log2-scaled)
        floatx4 s[8];
        #pragma unroll
        for (int ct = 0; ct < 8; ++ct) {
            floatx4 a = {0.f, 0.f, 0.f, 0.f};
            #pragma unroll
            for (int kg = 0; kg < 2; ++kg) {
                short8 kb = *(const short8*)(Ks + (ct*2 + kg)*512 + lane*8);
                a = __builtin_amdgcn_mfma_f32_16x16x32_bf16(kb, aq[kg], a, 0, 0, 0);
            }
            s[ct] = a;
        }

        if (kt == nit-1) {   // causal mask: key > q  (all operands lane-local)
            #pragma unroll
            for (int ct = 0; ct < 8; ++ct)
                #pragma unroll
                for (int r = 0; r < 4; ++r) {
                    int key = kt*128 + ct*16 + g*4 + r;
                    if (key > qglob) s[ct][r] = -1e30f;
                }
        }

        // tree max over 32 in-lane values + 2 shfls across the 4 g-lanes
        float cm[8];
        #pragma unroll
        for (int ct = 0; ct < 8; ++ct)
            cm[ct] = fmaxf(fmaxf(s[ct][0], s[ct][1]), fmaxf(s[ct][2], s[ct][3]));
        float tmax = fmaxf(fmaxf(fmaxf(cm[0], cm[1]), fmaxf(cm[2], cm[3])),
                           fmaxf(fmaxf(cm[4], cm[5]), fmaxf(cm[6], cm[7])));
        tmax = fmaxf(tmax, __shfl_xor(tmax, 16));
        tmax = fmaxf(tmax, __shfl_xor(tmax, 32));
        float mn = fmaxf(m_l, tmax);
        float alpha = exp2f(m_l - mn);
        m_l = mn;

        // broadcast alpha to C-layout rows (q = g*4+r); rescale O and l
        float ar[4];
        #pragma unroll
        for (int r = 0; r < 4; ++r) ar[r] = __shfl(alpha, g*4 + r);
        #pragma unroll
        for (int r = 0; r < 4; ++r) {
            lacc[r] *= ar[r];
            #pragma unroll
            for (int nt = 0; nt < 4; ++nt) accO[nt][r] *= ar[r];
        }

        // 4 ks-phases: exp+pack 32 keys into the per-wave chunk, read back as
        // A-frag, accumulate l (ones-MFMA) and O (4 nt MFMA).
        #pragma unroll
        for (int ks = 0; ks < 4; ++ks) {
            #pragma unroll
            for (int half = 0; half < 2; ++half) {
                int ct = ks*2 + half;
                float p0 = exp2f(s[ct][0] - mn);
                float p1 = exp2f(s[ct][1] - mn);
                float p2 = exp2f(s[ct][2] - mn);
                float p3 = exp2f(s[ct][3] - mn);
                union { __hip_bfloat162 h2[2]; uint2 u; } pk;
                pk.h2[0] = __float22bfloat162_rn(float2{p0, p1});
                pk.h2[1] = __float22bfloat162_rn(float2{p2, p3});
                *(uint2*)(Ps[w] + c16*PSTR2 + half*16 + g*4) = pk.u;
            }
            short8 pa = *(const short8*)(Ps[w] + c16*PSTR2 + g*8);
            lacc = __builtin_amdgcn_mfma_f32_16x16x32_bf16(pa, ones, lacc, 0, 0, 0);
            #pragma unroll
            for (int nt = 0; nt < 4; ++nt) {
                short8 vb = *(const short8*)(Vs + (ks*4 + nt)*512 + lane*8);
                accO[nt] = __builtin_amdgcn_mfma_f32_16x16x32_bf16(pa, vb, accO[nt], 0, 0, 0);
            }
        }
        __syncthreads();
    }

    // epilogue: y = O * (1/l); l already in accO row layout -> no shuffles
    float ir[4];
    #pragma unroll
    for (int r = 0; r < 4; ++r) ir[r] = __builtin_amdgcn_rcpf(lacc[r]);
    #pragma unroll
    for (int nt = 0; nt < 4; ++nt)
        #pragma unroll
        for (int r = 0; r < 4; ++r) {
            int row = qbase + g*4 + r;
            float o = accO[nt][r] * ir[r];
            y[((size_t)(b*T_ + row))*C_ + h*64 + nt*16 + c16] = __float2bfloat16(o);
        }
}

// ---------------------------------------------------------------------------
// Kernel C: output projection. out = y_att @ Wp^T + bp (f32 output). Grid (32, 8).
// ---------------------------------------------------------------------------
__global__ __launch_bounds__(256) void proj_gemm(
    const bf16* __restrict__ yin, const bf16* __restrict__ Wp, const float* __restrict__ bp,
    float* __restrict__ out)
{
    __shared__ __align__(16) bf16 As[128*32];
    __shared__ __align__(16) bf16 Bs[128*32];

    const int tid = threadIdx.x;
    const int w = tid >> 6, lane = tid & 63;
    const int g = lane >> 4, c16 = lane & 15;
    const int wr = w >> 1, wc = w & 1;
    const int mtile = blockIdx.x, ntile = blockIdx.y;
    const int nbase = ntile * 128;

    const bf16* ag = yin + (size_t)(mtile*128)*C_;
    const bf16* bg = Wp  + (size_t)nbase*C_;

    floatx4 acc[4][4] = {};

    for (int k0 = 0; k0 < C_; k0 += 32) {
        #pragma unroll
        for (int p = 0; p < 2; ++p) {
            int cb = p*256 + w*64;
            int c  = cb + lane;
            gl2lds16(ag + (size_t)(c>>2)*C_ + k0 + (c&3)*8, As + cb*8);
            gl2lds16(bg + (size_t)(c>>2)*C_ + k0 + (c&3)*8, Bs + cb*8);
        }
        __syncthreads();

        short8 af[4], bfr[4];
        #pragma unroll
        for (int i = 0; i < 4; ++i)
            af[i] = *(const short8*)(As + (wr*64 + i*16 + c16)*32 + g*8);
        #pragma unroll
        for (int j = 0; j < 4; ++j)
            bfr[j] = *(const short8*)(Bs + (wc*64 + j*16 + c16)*32 + g*8);
        #pragma unroll
        for (int i = 0; i < 4; ++i)
            #pragma unroll
            for (int j = 0; j < 4; ++j)
                acc[i][j] = __builtin_amdgcn_mfma_f32_16x16x32_bf16(af[i], bfr[j], acc[i][j], 0, 0, 0);
        __syncthreads();
    }

    #pragma unroll
    for (int i = 0; i < 4; ++i) {
        int m0 = mtile*128 + wr*64 + i*16 + g*4;
        #pragma unroll
        for (int j = 0; j < 4; ++j) {
            int n = nbase + wc*64 + j*16 + c16;
            float bvf = bp[n];
            #pragma unroll
            for (int r = 0; r < 4; ++r)
                out[(size_t)(m0+r)*C_ + n] = acc[i][j][r] + bvf;
        }
    }
}

extern "C" void kernel_launch(void* const* d_in, const int* in_sizes, int n_in,
                              void* d_out, int out_size, void* d_ws, size_t ws_size,
                              hipStream_t stream) {
    const float* x  = (const float*)d_in[0];
    const float* Wq = (const float*)d_in[1];
    const float* bq = (const float*)d_in[2];
    const float* Wk = (const float*)d_in[3];
    const float* bk = (const float*)d_in[4];
    const float* Wv = (const float*)d_in[5];
    const float* bv = (const float*)d_in[6];
    const float* Wp = (const float*)d_in[7];
    const float* bp = (const float*)d_in[8];

    // workspace layout (bf16 elements)
    bf16* xb  = (bf16*)d_ws;          // 4M
    bf16* wqb = xb  + NX_;            // 1M
    bf16* wkb = wqb + NW_;            // 1M
    bf16* wvb = wkb + NW_;            // 1M
    bf16* wpb = wvb + NW_;            // 1M
    bf16* qw  = wpb + NW_;            // 4M
    bf16* kw  = qw  + NX_;            // 4M
    bf16* vt  = kw  + NX_;            // 4M
    bf16* yw  = vt  + NX_;            // 4M  -> total 24M bf16 = 48 MB

    const int cvt_blocks = (int)((NX_ + 4*NW_) / (4*256));   // 8192
    cvt_f32_bf16<<<cvt_blocks, 256, 0, stream>>>(x, Wq, Wk, Wv, Wp, xb, wqb, wkb, wvb, wpb);
    qkv_gemm<<<dim3(32, 24), 256, 0, stream>>>(xb, wqb, bq, wkb, bk, wvb, bv, qw, kw, vt);
    attn    <<<1024, 256, 0, stream>>>(qw, kw, vt, yw);
    proj_gemm<<<dim3(32, 8), 256, 0, stream>>>(yw, wpb, bp, (float*)d_out);
}